// Round 2
// baseline (606.729 us; speedup 1.0000x reference)
//
#include <hip/hip_runtime.h>

// Problem constants (match the JAX reference).
#define B_   32
#define S_   4096
#define F_   512
#define K_   25
#define F4_  (F_ / 4)          // 128 float4 columns per row
#define SEG  100               // s-segment per thread; MUST be a multiple of K_
#define NSEG ((S_ + SEG - 1) / SEG)   // 41 (last segment partially masked)

// Native vector type for nontemporal builtins (HIP float4 is a class and
// is rejected by __builtin_nontemporal_store).
typedef float floatx4 __attribute__((ext_vector_type(4)));

// Causal K=25 sliding-window filter along S, edge-clamped at s=0.
//
// SCATTER formulation: each thread owns outputs s0..s0+SEG-1 for one
// (b, float4-column). It keeps 25 float4 ACCUMULATORS (not a gather
// window): x[t] is loaded exactly once and immediately applied to the 25
// outputs it feeds (out[t..t+24], weight w[24-d] for out[t+d]).
// Accumulators cannot be rematerialized/re-loaded by the compiler (FP
// reassociation is illegal), so the 100-VGPR state is forced into
// registers — the previous gather-window version was demoted to
// re-loads (VGPR_Count=60 < 100 required) and ran latency-bound at
// 2.5 TB/s.
//
// Slot invariant: out[s] accumulates in acc[(s - s0) % 25]; SEG % 25 == 0
// so all slot indices are compile-time constants after the 25x unroll.
// A slot's FIRST contribution is d == 24 (t = s-24): written with '='
// (overwrite), which both retires the just-stored previous output in that
// slot and removes the need to zero it.
__global__ __launch_bounds__(64, 3)
void adapt_smoothing_kernel(const float* __restrict__ x,
                            const float* __restrict__ w,
                            float* __restrict__ out) {
    const int tid  = blockIdx.x * blockDim.x + threadIdx.x;
    const int f4   = tid & (F4_ - 1);
    const int rest = tid >> 7;              // / F4_
    if (rest >= B_ * NSEG) return;
    const int seg = rest % NSEG;
    const int b   = rest / NSEG;
    const int s0  = seg * SEG;              // s0 % 25 == 0

    // Weights: force to SGPRs (wave-uniform) so FMAs use 1 SGPR + 2 VGPR.
    float wt[K_];
#pragma unroll
    for (int l = 0; l < K_; ++l)
        wt[l] = __int_as_float(__builtin_amdgcn_readfirstlane(__float_as_int(w[l])));

    const float4* __restrict__ xcol = (const float4*)(x + (size_t)b * S_ * F_) + f4;
    float4*                    ocol = (float4*)(out + (size_t)b * S_ * F_) + f4;

    float4 acc[K_];
#pragma unroll
    for (int m = 0; m < K_; ++m) acc[m] = make_float4(0.f, 0.f, 0.f, 0.f);

    // Prefill: t = s0-24 .. s0-1 (edge-clamped). x[t] (j = t-(s0-24))
    // feeds out[s0+m] for m = 0..j with weight w[j-m]. Triangular, all
    // indices compile-time.
#pragma unroll
    for (int j = 0; j < K_ - 1; ++j) {
        int t = s0 - (K_ - 1) + j;
        t = t < 0 ? 0 : t;
        const float4 v = xcol[(size_t)t * F4_];
#pragma unroll
        for (int m = 0; m <= j; ++m) {
            const float c = wt[j - m];
            acc[m].x += c * v.x; acc[m].y += c * v.y;
            acc[m].z += c * v.z; acc[m].w += c * v.w;
        }
    }

    // Main loop, software-pipelined: v holds x[s0+i]; the load for i+1 is
    // issued before the 25 FMAs for i. Loads beyond S-1 are clamped (they
    // only feed outputs >= S, which are never stored).
    float4 v = xcol[(size_t)s0 * F4_];
#pragma unroll 1
    for (int i0 = 0; i0 < SEG; i0 += K_) {
#pragma unroll
        for (int u = 0; u < K_; ++u) {
            const int s  = s0 + i0 + u;
            const int sn = (s + 1) < S_ ? (s + 1) : (S_ - 1);
            const float4 vn = xcol[(size_t)sn * F4_];
            // x[s] feeds out[s+d], d = 0..24, weight w[24-d], slot (u+d)%25.
#pragma unroll
            for (int d = 0; d < K_; ++d) {
                const float c = wt[K_ - 1 - d];
                float4& a = acc[(u + d) % K_];
                if (d == K_ - 1) {
                    // First contribution for output s+24: overwrite the
                    // slot retired (stored) at step u-1.
                    a.x = c * v.x; a.y = c * v.y;
                    a.z = c * v.z; a.w = c * v.w;
                } else {
                    a.x += c * v.x; a.y += c * v.y;
                    a.z += c * v.z; a.w += c * v.w;
                }
            }
            // out[s] is complete (d=0 added w[24]*x[s]). Output is never
            // re-read: nontemporal store keeps L2/L3 for input re-reads.
            if (s < S_)
                __builtin_nontemporal_store(*(const floatx4*)&acc[u],
                                            (floatx4*)&ocol[(size_t)s * F4_]);
            v = vn;
        }
    }
}

extern "C" void kernel_launch(void* const* d_in, const int* in_sizes, int n_in,
                              void* d_out, int out_size, void* d_ws, size_t ws_size,
                              hipStream_t stream) {
    const float* x = (const float*)d_in[0];   // [B, S, F] fp32
    const float* w = (const float*)d_in[1];   // [K] fp32
    float* out     = (float*)d_out;           // [B, S, F] fp32

    const int total_threads = B_ * NSEG * F4_;         // 167,936
    const int block = 64;                              // 1 wave/block: finer
    const int grid  = (total_threads + block - 1) / block;  // 2624 — better
    adapt_smoothing_kernel<<<grid, block, 0, stream>>>(x, w, out);  // CU balance
}

// Round 3
// 467.964 us; speedup vs baseline: 1.2965x; 1.2965x over previous
//
#include <hip/hip_runtime.h>

// Problem constants (match the JAX reference).
#define B_   32
#define S_   4096
#define F_   512
#define K_   25
#define F4_  (F_ / 4)          // 128 float4 columns per row
#define SEG  100               // s-segment per thread; MUST be a multiple of K_
#define NSEG ((S_ + SEG - 1) / SEG)   // 41 (last segment partially masked)

// Native clang vector type. Used for EVERYTHING (loads, accumulators,
// stores) so no local ever has its address taken: round 2 proved that
// `*(floatx4*)&acc[u]` defeated SROA and pushed the whole accumulator
// array to scratch (VGPR_Count=84 < the 100 required; WRITE_SIZE 561 MB
// vs 268 MB of output = spill traffic).
typedef float floatx4 __attribute__((ext_vector_type(4)));

// Causal K=25 sliding-window filter along S, edge-clamped at s=0.
//
// SCATTER formulation: each thread owns outputs s0..s0+SEG-1 for one
// (b, float4-column). It keeps 25 float4 ACCUMULATORS: x[t] is loaded
// exactly once and applied to the 25 outputs it feeds (out[t+d] gets
// w[24-d]*x[t]). Accumulators cannot be rematerialized by the compiler
// (FP reassociation is illegal), unlike the original gather window whose
// loads the compiler legally re-issued (VGPR=60, latency-bound).
//
// Slot invariant: out[s] accumulates in acc[(s - s0) % 25]; SEG % 25 == 0
// so after the 25x unroll every slot index is a compile-time constant.
// A slot's FIRST contribution (d == 24) is written with '=' (overwrite),
// retiring the previously-stored output in that slot — no re-zeroing.
// Per-output accumulation order is t-ascending == the reference's l-
// ascending order, so numerics match the gather version.
__global__ __launch_bounds__(64, 3)
void adapt_smoothing_kernel(const float* __restrict__ x,
                            const float* __restrict__ w,
                            float* __restrict__ out) {
    const int tid  = blockIdx.x * blockDim.x + threadIdx.x;
    const int f4   = tid & (F4_ - 1);
    const int rest = tid >> 7;              // / F4_
    if (rest >= B_ * NSEG) return;
    const int seg = rest % NSEG;
    const int b   = rest / NSEG;
    const int s0  = seg * SEG;              // s0 % 25 == 0

    // Weights: force to SGPRs (wave-uniform) so FMAs read 1 SGPR + 1 VGPR.
    float wt[K_];
#pragma unroll
    for (int l = 0; l < K_; ++l)
        wt[l] = __int_as_float(__builtin_amdgcn_readfirstlane(__float_as_int(w[l])));

    const floatx4* __restrict__ xcol =
        (const floatx4*)(x + (size_t)b * S_ * F_) + f4;
    floatx4* __restrict__ ocol =
        (floatx4*)(out + (size_t)b * S_ * F_) + f4;

    floatx4 acc[K_];
#pragma unroll
    for (int m = 0; m < K_; ++m) acc[m] = (floatx4)0.0f;

    // Prefill: t = s0-24 .. s0-1 (edge-clamped). x[t] (j = t-(s0-24))
    // feeds out[s0+m] for m = 0..j with weight w[j-m]. Triangular, all
    // indices compile-time.
#pragma unroll
    for (int j = 0; j < K_ - 1; ++j) {
        int t = s0 - (K_ - 1) + j;
        t = t < 0 ? 0 : t;
        const floatx4 v = xcol[(size_t)t * F4_];
#pragma unroll
        for (int m = 0; m <= j; ++m)
            acc[m] += v * wt[j - m];
    }

    // Main loop, software-pipelined: v holds x[s0+i]; the load for i+1 is
    // issued before the 25 FMAs for i. Loads beyond S-1 are clamped (they
    // only feed outputs >= S, which are never stored).
    floatx4 v = xcol[(size_t)s0 * F4_];
#pragma unroll 1
    for (int i0 = 0; i0 < SEG; i0 += K_) {
#pragma unroll
        for (int u = 0; u < K_; ++u) {
            const int s  = s0 + i0 + u;
            const int sn = (s + 1) < S_ ? (s + 1) : (S_ - 1);
            const floatx4 vn = xcol[(size_t)sn * F4_];
            // x[s] feeds out[s+d], d = 0..24, weight w[24-d], slot (u+d)%25.
#pragma unroll
            for (int d = 0; d < K_; ++d) {
                const float c = wt[K_ - 1 - d];
                if (d == K_ - 1)
                    acc[(u + d) % K_] = v * c;   // first contribution: overwrite
                else
                    acc[(u + d) % K_] += v * c;
            }
            // out[s] is complete (d=0 added w[24]*x[s]). Output is never
            // re-read: nontemporal store keeps L2/L3 for input re-reads.
            // acc[u] is passed BY VALUE — only the global pointer's
            // address is formed.
            if (s < S_)
                __builtin_nontemporal_store(acc[u], &ocol[(size_t)s * F4_]);
            v = vn;
        }
    }
}

extern "C" void kernel_launch(void* const* d_in, const int* in_sizes, int n_in,
                              void* d_out, int out_size, void* d_ws, size_t ws_size,
                              hipStream_t stream) {
    const float* x = (const float*)d_in[0];   // [B, S, F] fp32
    const float* w = (const float*)d_in[1];   // [K] fp32
    float* out     = (float*)d_out;           // [B, S, F] fp32

    const int total_threads = B_ * NSEG * F4_;         // 167,936
    const int block = 64;                              // 1 wave/block
    const int grid  = (total_threads + block - 1) / block;  // 2624
    adapt_smoothing_kernel<<<grid, block, 0, stream>>>(x, w, out);
}